// Round 8
// baseline (342.933 us; speedup 1.0000x reference)
//
#include <hip/hip_runtime.h>

#define LP  40    // k_support LDS row stride (shorts)
#define LPB 40    // k_main Bs row stride (shorts)

typedef __attribute__((ext_vector_type(8))) short short8;
typedef __attribute__((ext_vector_type(4))) short short4t;
typedef __attribute__((ext_vector_type(4))) float f32x4;

__device__ __forceinline__ short f2bf(float f) {
  unsigned u = __builtin_bit_cast(unsigned, f);
  u += 0x7FFFu + ((u >> 16) & 1u);   // round-to-nearest-even
  return (short)(u >> 16);
}

__device__ __forceinline__ float lrelu(float v) { return v >= 0.f ? v : 0.2f * v; }

// ---------------- Kernel 0: wT bf16 [512][512]  (wt[n][c] = w[c][n]) ----------------
__global__ __launch_bounds__(256) void k_wt(const float* __restrict__ w,
                                            short* __restrict__ wt) {
  __shared__ float t[64][65];
  int c0 = (blockIdx.x & 7) * 64;
  int n0 = (blockIdx.x >> 3) * 64;
  int r  = threadIdx.x >> 4;
  int q4 = (threadIdx.x & 15) * 4;
  for (int i = 0; i < 4; i++) {
    int c = r + i * 16;
    f32x4 v = *(const f32x4*)(w + (size_t)(c0 + c) * 512 + (n0 + q4));
    t[c][q4 + 0] = v[0]; t[c][q4 + 1] = v[1]; t[c][q4 + 2] = v[2]; t[c][q4 + 3] = v[3];
  }
  __syncthreads();
  for (int i = 0; i < 4; i++) {
    int n = r + i * 16;
    short4t o;
    for (int j = 0; j < 4; j++) o[j] = f2bf(t[q4 + j][n]);
    *(short4t*)(wt + (size_t)(n0 + n) * 512 + (c0 + q4)) = o;
  }
}

// ------------- Kernel 1: supportT bf16 [512][8192] = (inputs @ w + b)^T -------------
__global__ __launch_bounds__(512, 2) void k_support(const float* __restrict__ inp,
                                                    const short* __restrict__ wt,
                                                    const float* __restrict__ bias,
                                                    short* __restrict__ sup) {
  __shared__ __align__(16) short As[512 * LP];
  __shared__ __align__(16) short Bs[64 * LP];
  const int tid = threadIdx.x;
  const int m0 = blockIdx.x * 64;
  const int wave = tid >> 6, lane = tid & 63;
  const int wn = wave >> 1, wm = wave & 1;
  const int lr = lane & 15, lk = lane >> 4;
  const int bm = tid >> 3, bk = (tid & 7) * 4;
  f32x4 acc[8][2] = {};
  short8 ar[4]; f32x4 br;
  auto loadA = [&](int s) {
    const short* p = wt + (size_t)tid * 512 + s * 32;
    ar[0] = *(const short8*)(p);      ar[1] = *(const short8*)(p + 8);
    ar[2] = *(const short8*)(p + 16); ar[3] = *(const short8*)(p + 24);
  };
  auto loadB = [&](int s) {
    br = *(const f32x4*)(inp + (size_t)(m0 + bm) * 512 + s * 32 + bk);
  };
  loadA(0); loadB(0);
  for (int s = 0; s < 16; s++) {
    short* ad = As + tid * LP;
    *(short8*)(ad) = ar[0]; *(short8*)(ad + 8) = ar[1];
    *(short8*)(ad + 16) = ar[2]; *(short8*)(ad + 24) = ar[3];
    short4t bo;
    for (int j = 0; j < 4; j++) bo[j] = f2bf(br[j]);
    *(short4t*)(Bs + bm * LP + bk) = bo;
    __syncthreads();
    if (s + 1 < 16) { loadA(s + 1); loadB(s + 1); }
    short8 af[8], bfr[2];
    for (int nf = 0; nf < 8; nf++)
      af[nf] = *(const short8*)(As + (wn * 128 + nf * 16 + lr) * LP + lk * 8);
    for (int mf = 0; mf < 2; mf++)
      bfr[mf] = *(const short8*)(Bs + (wm * 32 + mf * 16 + lr) * LP + lk * 8);
    for (int nf = 0; nf < 8; nf++)
      for (int mf = 0; mf < 2; mf++)
        acc[nf][mf] = __builtin_amdgcn_mfma_f32_16x16x32_bf16(af[nf], bfr[mf], acc[nf][mf], 0, 0, 0);
    __syncthreads();
  }
  for (int nf = 0; nf < 8; nf++) {
    int nb = wn * 128 + nf * 16 + lk * 4;
    for (int mf = 0; mf < 2; mf++) {
      int m = m0 + wm * 32 + mf * 16 + lr;
      for (int j = 0; j < 4; j++) {
        int n = nb + j;
        sup[(size_t)n * 8192 + m] = f2bf(acc[nf][mf][j] + bias[n]);
      }
    }
  }
}

// ======================= PRIMARY: BM=128, ksplit=4, BK=32 =======================
// Per-CU VMEM 6.5 MB (adj 4.2 HBM + sup 2.1 L2) vs 8.4 at BM=64 -> path-bound win.
// Drain-free step: af(s)+adj(s+1) issued, vmcnt(8) completes adj(s)+af(s) only.
#define ISSUEB(SL, S) {                                                         \
    const float* p_ = abase + (size_t)(S) * 32;                                 \
    R[SL][0][0] = __builtin_nontemporal_load((const f32x4*)(p_));               \
    R[SL][0][1] = __builtin_nontemporal_load((const f32x4*)(p_ + 4));           \
    R[SL][1][0] = __builtin_nontemporal_load((const f32x4*)(p_ + (1ull << 26)));\
    R[SL][1][1] = __builtin_nontemporal_load((const f32x4*)(p_ + (1ull << 26) + 4));\
    R[SL][2][0] = __builtin_nontemporal_load((const f32x4*)(p_ + (2ull << 26)));\
    R[SL][2][1] = __builtin_nontemporal_load((const f32x4*)(p_ + (2ull << 26) + 4));\
    R[SL][3][0] = __builtin_nontemporal_load((const f32x4*)(p_ + (3ull << 26)));\
    R[SL][3][1] = __builtin_nontemporal_load((const f32x4*)(p_ + (3ull << 26) + 4));\
  }

#define STEPB(U) {                                                              \
    const int s_ = s0 + (U);                                                    \
    _Pragma("unroll") for (int nf = 0; nf < 4; nf++)                            \
      AF[nf] = *(const short8*)(supp + (size_t)(nf * 16) * 8192 + (size_t)s_ * 32); \
    ISSUEB(((U) + 1) & 1, (s_ + 1) & 63)                                        \
    __builtin_amdgcn_sched_barrier(0);                                          \
    asm volatile("s_waitcnt vmcnt(8)" ::: "memory");                            \
    __builtin_amdgcn_sched_barrier(0);                                          \
    f32x4 c0_, c1_;                                                             \
    _Pragma("unroll") for (int e = 0; e < 4; e++) {                             \
      c0_[e] = t0 * R[(U)][0][0][e] + t1 * R[(U)][1][0][e]                      \
             + t2 * R[(U)][2][0][e] + t3 * R[(U)][3][0][e];                     \
      c1_[e] = t0 * R[(U)][0][1][e] + t1 * R[(U)][1][1][e]                      \
             + t2 * R[(U)][2][1][e] + t3 * R[(U)][3][1][e];                     \
    }                                                                           \
    short8 o_;                                                                  \
    _Pragma("unroll") for (int e = 0; e < 4; e++) {                             \
      o_[e] = f2bf(c0_[e]); o_[4 + e] = f2bf(c1_[e]);                           \
    }                                                                           \
    *(short8*)(Bs[(U) & 1] + r * LPB + q * 8) = o_;                             \
    asm volatile("s_waitcnt lgkmcnt(0)" ::: "memory");                          \
    __builtin_amdgcn_sched_barrier(0);                                          \
    __builtin_amdgcn_s_barrier();                                               \
    __builtin_amdgcn_sched_barrier(0);                                          \
    _Pragma("unroll") for (int mf = 0; mf < 8; mf++) {                          \
      short8 bfr = *(const short8*)(Bs[(U) & 1] + (mf * 16 + lr) * LPB + lk * 8); \
      _Pragma("unroll") for (int nf = 0; nf < 4; nf++)                          \
        acc[nf][mf] = __builtin_amdgcn_mfma_f32_16x16x32_bf16(AF[nf], bfr,      \
                                                              acc[nf][mf], 0, 0, 0); \
    }                                                                           \
  }

__global__ __launch_bounds__(512, 2) void k_main128(const float* __restrict__ adj,
                                                    const float* __restrict__ att,
                                                    const short* __restrict__ sup,
                                                    float* __restrict__ part) {
  __shared__ __align__(16) short Bs[2][128 * LPB];   // 20.5 KB dbuf
  const int tid = threadIdx.x;
  const int b = blockIdx.x;
  const int xcd = b & 7;
  const int kc = xcd >> 1;                  // kc pinned to XCD pair -> 2MB sup L2-warm
  const int m0 = ((b >> 3) * 2 + (xcd & 1)) * 128;
  const int kbase = kc * 2048;              // kchunk=2048, nsteps=64
  const float t0 = att[0], t1 = att[1], t2 = att[2], t3 = att[3];
  const int wave = tid >> 6, lane = tid & 63;
  const int lr = lane & 15, lk = lane >> 4;
  const int r = tid >> 2, q = tid & 3;      // combine map: row 0..127, 8-float chunk
  f32x4 acc[4][8] = {};                     // [nf][mf] = 128 VGPR
  const float* abase = adj + (size_t)(m0 + r) * 8192 + kbase + q * 8;
  const short* supp = sup + (size_t)(wave * 64 + lr) * 8192 + kbase + lk * 8;
  f32x4 R[2][4][2];                         // dist-1 adj slots: 64 VGPR, static idx
  short8 AF[4];                             // sup frags for step s

  ISSUEB(0, 0)
  for (int s0 = 0; s0 < 64; s0 += 2) {
    STEPB(0) STEPB(1)
  }

#pragma unroll
  for (int nf = 0; nf < 4; nf++) {
    int n = wave * 64 + nf * 16 + lk * 4;
#pragma unroll
    for (int mf = 0; mf < 8; mf++) {
      int m = m0 + mf * 16 + lr;
      __builtin_nontemporal_store(acc[nf][mf],
          (f32x4*)(part + ((size_t)kc << 22) + (size_t)m * 512 + n));
    }
  }
}

// ==================== FALLBACK (exact R7): BM=64, ksplit<=2 ====================
#define ISSUE64(SL, S) {                                                        \
    const float* p_ = abase + (size_t)(S) * 32;                                 \
    R[SL][0] = __builtin_nontemporal_load((const f32x4*)(p_));                  \
    R[SL][1] = __builtin_nontemporal_load((const f32x4*)(p_ + (1ull << 26)));   \
    R[SL][2] = __builtin_nontemporal_load((const f32x4*)(p_ + (2ull << 26)));   \
    R[SL][3] = __builtin_nontemporal_load((const f32x4*)(p_ + (3ull << 26)));   \
  }

#define ISSUEAF64(SL, S) {                                                      \
    const short* q_ = supp + (size_t)(S) * 32;                                  \
    AF[SL][0] = *(const short8*)(q_);                                           \
    AF[SL][1] = *(const short8*)(q_ + (size_t)16 * 8192);                       \
    AF[SL][2] = *(const short8*)(q_ + (size_t)32 * 8192);                       \
    AF[SL][3] = *(const short8*)(q_ + (size_t)48 * 8192);                       \
  }

#define STEP64(U) {                                                             \
    ISSUE64(((U) + 2) & 3, (s0 + (U) + 2) & (nsteps - 1))                       \
    ISSUEAF64(((U) + 1) & 1, (s0 + (U) + 1) & (nsteps - 1))                     \
    __builtin_amdgcn_sched_barrier(0);                                          \
    asm volatile("s_waitcnt vmcnt(20)" ::: "memory");                           \
    __builtin_amdgcn_sched_barrier(0);                                          \
    f32x4 c_;                                                                   \
    _Pragma("unroll") for (int e = 0; e < 4; e++)                               \
      c_[e] = t0 * R[(U) & 3][0][e] + t1 * R[(U) & 3][1][e]                     \
            + t2 * R[(U) & 3][2][e] + t3 * R[(U) & 3][3][e];                    \
    short4t o_;                                                                 \
    _Pragma("unroll") for (int e = 0; e < 4; e++) o_[e] = f2bf(c_[e]);          \
    *(short4t*)(Bs[(U) & 1] + r * LPB + q * 4) = o_;                            \
    asm volatile("s_waitcnt lgkmcnt(0)" ::: "memory");                          \
    __builtin_amdgcn_sched_barrier(0);                                          \
    __builtin_amdgcn_s_barrier();                                               \
    __builtin_amdgcn_sched_barrier(0);                                          \
    short8 bfr[4];                                                              \
    _Pragma("unroll") for (int mf = 0; mf < 4; mf++)                            \
      bfr[mf] = *(const short8*)(Bs[(U) & 1] + (mf * 16 + lr) * LPB + lk * 8);  \
    asm volatile("s_waitcnt vmcnt(8)" ::: "memory");                            \
    __builtin_amdgcn_sched_barrier(0);                                          \
    _Pragma("unroll") for (int nf = 0; nf < 4; nf++)                            \
      _Pragma("unroll") for (int mf = 0; mf < 4; mf++)                          \
        acc[nf][mf] = __builtin_amdgcn_mfma_f32_16x16x32_bf16(AF[(U) & 1][nf],  \
                          bfr[mf], acc[nf][mf], 0, 0, 0);                       \
  }

__global__ __launch_bounds__(512, 2) void k_main64(const float* __restrict__ adj,
                                                   const float* __restrict__ att,
                                                   const short* __restrict__ sup,
                                                   float* __restrict__ part,
                                                   float* __restrict__ outp,
                                                   int ksplit) {
  __shared__ __align__(16) short Bs[2][64 * LPB];
  const int tid = threadIdx.x;
  const int b = blockIdx.x;
  const int xpk = 8 / ksplit;
  const int xcd = b & 7;
  const int kc = xcd / xpk;
  const int m0 = ((b >> 3) * xpk + (xcd % xpk)) * 64;
  const int kchunk = 8192 / ksplit;
  const int nsteps = kchunk / 32;
  const int kbase = kc * kchunk;
  const float t0 = att[0], t1 = att[1], t2 = att[2], t3 = att[3];
  const int wave = tid >> 6, lane = tid & 63;
  const int lr = lane & 15, lk = lane >> 4;
  const int r = tid >> 3, q = tid & 7;
  f32x4 acc[4][4] = {};
  const float* abase = adj + (size_t)(m0 + r) * 8192 + kbase + q * 4;
  const short* supp = sup + (size_t)(wave * 64 + lr) * 8192 + kbase + lk * 8;
  f32x4 R[4][4];
  short8 AF[2][4];

  ISSUE64(0, 0) ISSUEAF64(0, 0) ISSUE64(1, 1)
  for (int s0 = 0; s0 < nsteps; s0 += 4) {
    STEP64(0) STEP64(1) STEP64(2) STEP64(3)
  }

#pragma unroll
  for (int nf = 0; nf < 4; nf++) {
    int n = wave * 64 + nf * 16 + lk * 4;
#pragma unroll
    for (int mf = 0; mf < 4; mf++) {
      int m = m0 + mf * 16 + lr;
      f32x4 v = acc[nf][mf];
      if (ksplit == 1) {
        for (int j = 0; j < 4; j++) v[j] = lrelu(v[j]);
        __builtin_nontemporal_store(v, (f32x4*)(outp + (size_t)m * 512 + n));
      } else {
        __builtin_nontemporal_store(v, (f32x4*)(part + ((size_t)kc << 22) + (size_t)m * 512 + n));
      }
    }
  }
}

// ---------------- Kernel 3: reduce K-split partials + LeakyReLU ----------------
__global__ __launch_bounds__(256) void k_reduce(const float* __restrict__ part,
                                                float* __restrict__ outp, int ksplit) {
  const size_t total = (size_t)8192 * 512 / 4;
  for (size_t i = (size_t)blockIdx.x * 256 + threadIdx.x; i < total;
       i += (size_t)gridDim.x * 256) {
    f32x4 a = __builtin_nontemporal_load((const f32x4*)(part + i * 4));
    for (int k = 1; k < ksplit; k++) {
      f32x4 bv = __builtin_nontemporal_load((const f32x4*)(part + ((size_t)k << 22) + i * 4));
      for (int j = 0; j < 4; j++) a[j] += bv[j];
    }
    f32x4 v;
    for (int j = 0; j < 4; j++) v[j] = lrelu(a[j]);
    __builtin_nontemporal_store(v, (f32x4*)(outp + i * 4));
  }
}

extern "C" void kernel_launch(void* const* d_in, const int* in_sizes, int n_in,
                              void* d_out, int out_size, void* d_ws, size_t ws_size,
                              hipStream_t stream) {
  const float* inputs = (const float*)d_in[0];
  const float* adj    = (const float*)d_in[1];
  const float* att    = (const float*)d_in[2];
  const float* w      = (const float*)d_in[3];
  const float* bias   = (const float*)d_in[4];
  float* outp = (float*)d_out;

  char* ws = (char*)d_ws;
  short* sup  = (short*)(ws);                 // 8 MB  supportT bf16 [512][8192]
  short* wt   = (short*)(ws + (8u << 20));    // 512 KB wT bf16 [512][512]
  float* part = (float*)(ws + (9u << 20));    // ksplit x 16 MB fp32 partials

  const size_t base = (9ull << 20), psz = (1ull << 24);

  k_wt<<<64, 256, 0, stream>>>(w, wt);
  k_support<<<128, 512, 0, stream>>>(inputs, wt, bias, sup);

  if (ws_size >= base + 4 * psz) {
    // primary: BM=128, ksplit=4, grid 256 = 1 block/CU
    k_main128<<<256, 512, 0, stream>>>(adj, att, sup, part);
    k_reduce<<<1024, 256, 0, stream>>>(part, outp, 4);
  } else {
    int ksplit = (ws_size >= base + 2 * psz) ? 2 : 1;
    k_main64<<<128 * ksplit, 512, 0, stream>>>(adj, att, sup, part, outp, ksplit);
    if (ksplit > 1) k_reduce<<<1024, 256, 0, stream>>>(part, outp, ksplit);
  }
}

// Round 9
// 336.939 us; speedup vs baseline: 1.0178x; 1.0178x over previous
//
#include <hip/hip_runtime.h>

#define LP  40    // k_support LDS row stride (shorts)
#define LPB 72    // k_main Bs row stride (shorts): 144 B -> 2-way (free) read conflicts

typedef __attribute__((ext_vector_type(8))) short short8;
typedef __attribute__((ext_vector_type(4))) short short4t;
typedef __attribute__((ext_vector_type(4))) float f32x4;

__device__ __forceinline__ short f2bf(float f) {
  unsigned u = __builtin_bit_cast(unsigned, f);
  u += 0x7FFFu + ((u >> 16) & 1u);   // round-to-nearest-even
  return (short)(u >> 16);
}

__device__ __forceinline__ float lrelu(float v) { return v >= 0.f ? v : 0.2f * v; }

// ---------------- Kernel 0: wT bf16 [512][512]  (wt[n][c] = w[c][n]) ----------------
__global__ __launch_bounds__(256) void k_wt(const float* __restrict__ w,
                                            short* __restrict__ wt) {
  __shared__ float t[64][65];
  int c0 = (blockIdx.x & 7) * 64;
  int n0 = (blockIdx.x >> 3) * 64;
  int r  = threadIdx.x >> 4;
  int q4 = (threadIdx.x & 15) * 4;
  for (int i = 0; i < 4; i++) {
    int c = r + i * 16;
    f32x4 v = *(const f32x4*)(w + (size_t)(c0 + c) * 512 + (n0 + q4));
    t[c][q4 + 0] = v[0]; t[c][q4 + 1] = v[1]; t[c][q4 + 2] = v[2]; t[c][q4 + 3] = v[3];
  }
  __syncthreads();
  for (int i = 0; i < 4; i++) {
    int n = r + i * 16;
    short4t o;
    for (int j = 0; j < 4; j++) o[j] = f2bf(t[q4 + j][n]);
    *(short4t*)(wt + (size_t)(n0 + n) * 512 + (c0 + q4)) = o;
  }
}

// ------------- Kernel 1: supportT bf16 [512][8192] = (inputs @ w + b)^T -------------
__global__ __launch_bounds__(512, 2) void k_support(const float* __restrict__ inp,
                                                    const short* __restrict__ wt,
                                                    const float* __restrict__ bias,
                                                    short* __restrict__ sup) {
  __shared__ __align__(16) short As[512 * LP];
  __shared__ __align__(16) short Bs[64 * LP];
  const int tid = threadIdx.x;
  const int m0 = blockIdx.x * 64;
  const int wave = tid >> 6, lane = tid & 63;
  const int wn = wave >> 1, wm = wave & 1;
  const int lr = lane & 15, lk = lane >> 4;
  const int bm = tid >> 3, bk = (tid & 7) * 4;
  f32x4 acc[8][2] = {};
  short8 ar[4]; f32x4 br;
  auto loadA = [&](int s) {
    const short* p = wt + (size_t)tid * 512 + s * 32;
    ar[0] = *(const short8*)(p);      ar[1] = *(const short8*)(p + 8);
    ar[2] = *(const short8*)(p + 16); ar[3] = *(const short8*)(p + 24);
  };
  auto loadB = [&](int s) {
    br = *(const f32x4*)(inp + (size_t)(m0 + bm) * 512 + s * 32 + bk);
  };
  loadA(0); loadB(0);
  for (int s = 0; s < 16; s++) {
    short* ad = As + tid * LP;
    *(short8*)(ad) = ar[0]; *(short8*)(ad + 8) = ar[1];
    *(short8*)(ad + 16) = ar[2]; *(short8*)(ad + 24) = ar[3];
    short4t bo;
    for (int j = 0; j < 4; j++) bo[j] = f2bf(br[j]);
    *(short4t*)(Bs + bm * LP + bk) = bo;
    __syncthreads();
    if (s + 1 < 16) { loadA(s + 1); loadB(s + 1); }
    short8 af[8], bfr[2];
    for (int nf = 0; nf < 8; nf++)
      af[nf] = *(const short8*)(As + (wn * 128 + nf * 16 + lr) * LP + lk * 8);
    for (int mf = 0; mf < 2; mf++)
      bfr[mf] = *(const short8*)(Bs + (wm * 32 + mf * 16 + lr) * LP + lk * 8);
    for (int nf = 0; nf < 8; nf++)
      for (int mf = 0; mf < 2; mf++)
        acc[nf][mf] = __builtin_amdgcn_mfma_f32_16x16x32_bf16(af[nf], bfr[mf], acc[nf][mf], 0, 0, 0);
    __syncthreads();
  }
  for (int nf = 0; nf < 8; nf++) {
    int nb = wn * 128 + nf * 16 + lk * 4;
    for (int mf = 0; mf < 2; mf++) {
      int m = m0 + wm * 32 + mf * 16 + lr;
      for (int j = 0; j < 4; j++) {
        int n = nb + j;
        sup[(size_t)n * 8192 + m] = f2bf(acc[nf][mf][j] + bias[n]);
      }
    }
  }
}

// ===== Kernel 2: BM=64, BN=512, BK=64 — 64 steps, 1 barrier + 32 MFMA each. =====
// FIFO: prologue [adjA(0), af(0), adjA(1)]; per step: issue af(s+1) at top,
// vmcnt(16) completes adj(s)+af(s) (adj(s+1)+af(s+1) stay in flight), combine ->
// Bs write, issue adj(s+2) into freed slot, lgkmcnt(0)-only barrier, MFMA.
#define ISSUEA(SL, S) {                                                         \
    const float* p_ = abase + (size_t)(S) * 64;                                 \
    R[SL][0] = __builtin_nontemporal_load((const f32x4*)(p_));                  \
    R[SL][1] = __builtin_nontemporal_load((const f32x4*)(p_ + 4));              \
    R[SL][2] = __builtin_nontemporal_load((const f32x4*)(p_ + (1ull << 26)));   \
    R[SL][3] = __builtin_nontemporal_load((const f32x4*)(p_ + (1ull << 26) + 4));\
    R[SL][4] = __builtin_nontemporal_load((const f32x4*)(p_ + (2ull << 26)));   \
    R[SL][5] = __builtin_nontemporal_load((const f32x4*)(p_ + (2ull << 26) + 4));\
    R[SL][6] = __builtin_nontemporal_load((const f32x4*)(p_ + (3ull << 26)));   \
    R[SL][7] = __builtin_nontemporal_load((const f32x4*)(p_ + (3ull << 26) + 4));\
  }

#define ISSUEF(SL, S) {                                                         \
    const short* q_ = supp + (size_t)(S) * 64;                                  \
    AF[SL][0][0] = *(const short8*)(q_);                                        \
    AF[SL][0][1] = *(const short8*)(q_ + 32);                                   \
    AF[SL][1][0] = *(const short8*)(q_ + (size_t)16 * 8192);                    \
    AF[SL][1][1] = *(const short8*)(q_ + (size_t)16 * 8192 + 32);               \
    AF[SL][2][0] = *(const short8*)(q_ + (size_t)32 * 8192);                    \
    AF[SL][2][1] = *(const short8*)(q_ + (size_t)32 * 8192 + 32);               \
    AF[SL][3][0] = *(const short8*)(q_ + (size_t)48 * 8192);                    \
    AF[SL][3][1] = *(const short8*)(q_ + (size_t)48 * 8192 + 32);               \
  }

#define STEPK(U) {                                                              \
    const int s_ = s0 + (U);                                                    \
    ISSUEF(((U) + 1) & 1, (s_ + 1) & (NSTEPS - 1))                              \
    __builtin_amdgcn_sched_barrier(0);                                          \
    asm volatile("s_waitcnt vmcnt(16)" ::: "memory");                           \
    __builtin_amdgcn_sched_barrier(0);                                          \
    f32x4 cA_, cB_;                                                             \
    _Pragma("unroll") for (int e = 0; e < 4; e++) {                             \
      cA_[e] = t0 * R[(U)][0][e] + t1 * R[(U)][2][e]                            \
             + t2 * R[(U)][4][e] + t3 * R[(U)][6][e];                           \
      cB_[e] = t0 * R[(U)][1][e] + t1 * R[(U)][3][e]                            \
             + t2 * R[(U)][5][e] + t3 * R[(U)][7][e];                           \
    }                                                                           \
    short8 o_;                                                                  \
    _Pragma("unroll") for (int e = 0; e < 4; e++) {                             \
      o_[e] = f2bf(cA_[e]); o_[4 + e] = f2bf(cB_[e]);                           \
    }                                                                           \
    *(short8*)(Bs[(U)] + r * LPB + q * 8) = o_;                                 \
    ISSUEA((U), (s_ + 2) & (NSTEPS - 1))                                        \
    __builtin_amdgcn_sched_barrier(0);                                          \
    asm volatile("s_waitcnt lgkmcnt(0)" ::: "memory");                          \
    __builtin_amdgcn_sched_barrier(0);                                          \
    __builtin_amdgcn_s_barrier();                                               \
    __builtin_amdgcn_sched_barrier(0);                                          \
    _Pragma("unroll") for (int h = 0; h < 2; h++) {                             \
      _Pragma("unroll") for (int mf = 0; mf < 4; mf++) {                        \
        short8 bfr = *(const short8*)(Bs[(U)] + (mf * 16 + lr) * LPB + h * 32 + lk * 8); \
        _Pragma("unroll") for (int nf = 0; nf < 4; nf++)                        \
          acc[nf][mf] = __builtin_amdgcn_mfma_f32_16x16x32_bf16(                \
              AF[(U)][nf][h], bfr, acc[nf][mf], 0, 0, 0);                       \
      }                                                                         \
    }                                                                           \
  }

template <int KSPLIT>
__global__ __launch_bounds__(512, 2) void k_main(const float* __restrict__ adj,
                                                 const float* __restrict__ att,
                                                 const short* __restrict__ sup,
                                                 float* __restrict__ part,
                                                 float* __restrict__ outp) {
  constexpr int NSTEPS = 8192 / KSPLIT / 64;
  __shared__ __align__(16) short Bs[2][64 * LPB];   // 18.4 KB dbuf
  const int tid = threadIdx.x;
  const int b = blockIdx.x;
  const int xpk = 8 / KSPLIT;
  const int xcd = b & 7;
  const int kc = xcd / xpk;                 // kc pinned per XCD group -> sup L2-warm
  const int m0 = ((b >> 3) * xpk + (xcd % xpk)) * 64;
  const int kbase = kc * (8192 / KSPLIT);
  const float t0 = att[0], t1 = att[1], t2 = att[2], t3 = att[3];
  const int wave = tid >> 6, lane = tid & 63;
  const int lr = lane & 15, lk = lane >> 4;
  const int r = tid >> 3, q = tid & 7;      // combine map: row 0..63, 8-float chunk
  f32x4 acc[4][4] = {};                     // 64 VGPR
  const float* abase = adj + (size_t)(m0 + r) * 8192 + kbase + q * 8;
  const short* supp = sup + (size_t)(wave * 64 + lr) * 8192 + kbase + lk * 8;
  f32x4 R[2][8];                            // adj slots (dist-2, reissued post-combine)
  short8 AF[2][4][2];                       // sup slots (dist-1): 64 VGPR

  ISSUEA(0, 0) ISSUEF(0, 0) ISSUEA(1, 1)
  for (int s0 = 0; s0 < NSTEPS; s0 += 2) {
    STEPK(0) STEPK(1)
  }

#pragma unroll
  for (int nf = 0; nf < 4; nf++) {
    int n = wave * 64 + nf * 16 + lk * 4;
#pragma unroll
    for (int mf = 0; mf < 4; mf++) {
      int m = m0 + mf * 16 + lr;
      f32x4 v = acc[nf][mf];
      if (KSPLIT == 1) {
        for (int j = 0; j < 4; j++) v[j] = lrelu(v[j]);
        __builtin_nontemporal_store(v, (f32x4*)(outp + (size_t)m * 512 + n));
      } else {
        __builtin_nontemporal_store(v, (f32x4*)(part + ((size_t)kc << 22) + (size_t)m * 512 + n));
      }
    }
  }
}

// ---------------- Kernel 3: reduce K-split partials + LeakyReLU ----------------
__global__ __launch_bounds__(256) void k_reduce(const float* __restrict__ part,
                                                float* __restrict__ outp, int ksplit) {
  const size_t total = (size_t)8192 * 512 / 4;
  for (size_t i = (size_t)blockIdx.x * 256 + threadIdx.x; i < total;
       i += (size_t)gridDim.x * 256) {
    f32x4 a = __builtin_nontemporal_load((const f32x4*)(part + i * 4));
    for (int k = 1; k < ksplit; k++) {
      f32x4 bv = __builtin_nontemporal_load((const f32x4*)(part + ((size_t)k << 22) + i * 4));
      for (int j = 0; j < 4; j++) a[j] += bv[j];
    }
    f32x4 v;
    for (int j = 0; j < 4; j++) v[j] = lrelu(a[j]);
    __builtin_nontemporal_store(v, (f32x4*)(outp + i * 4));
  }
}

extern "C" void kernel_launch(void* const* d_in, const int* in_sizes, int n_in,
                              void* d_out, int out_size, void* d_ws, size_t ws_size,
                              hipStream_t stream) {
  const float* inputs = (const float*)d_in[0];
  const float* adj    = (const float*)d_in[1];
  const float* att    = (const float*)d_in[2];
  const float* w      = (const float*)d_in[3];
  const float* bias   = (const float*)d_in[4];
  float* outp = (float*)d_out;

  char* ws = (char*)d_ws;
  short* sup  = (short*)(ws);                 // 8 MB  supportT bf16 [512][8192]
  short* wt   = (short*)(ws + (8u << 20));    // 512 KB wT bf16 [512][512]
  float* part = (float*)(ws + (9u << 20));    // ksplit x 16 MB fp32 partials

  const size_t base = (9ull << 20), psz = (1ull << 24);

  k_wt<<<64, 256, 0, stream>>>(w, wt);
  k_support<<<128, 512, 0, stream>>>(inputs, wt, bias, sup);

  if (ws_size >= base + 2 * psz) {
    k_main<2><<<256, 512, 0, stream>>>(adj, att, sup, part, outp);
    k_reduce<<<1024, 256, 0, stream>>>(part, outp, 2);
  } else {
    k_main<1><<<128, 512, 0, stream>>>(adj, att, sup, part, outp);
  }
}